// Round 2
// baseline (231.642 us; speedup 1.0000x reference)
//
#include <hip/hip_runtime.h>
#include <hip/hip_bf16.h>

// Problem constants (from reference)
#define BATCH 16384
#define HD    1024
#define NP    48
#define PPC   24
#define EPSV  1e-4f

typedef __attribute__((ext_vector_type(8))) short  short8;
typedef __attribute__((ext_vector_type(4))) float  floatx4;

__device__ __forceinline__ float b2f(unsigned short s) {
    union { unsigned u; float f; } c; c.u = ((unsigned)s) << 16; return c.f;
}
__device__ __forceinline__ unsigned short f2bu(float f) {
    __hip_bfloat16 h = __float2bfloat16(f);  // RNE
    union { __hip_bfloat16 h; unsigned short u; } c; c.h = h; return c.u;
}

// ---------------------------------------- proto -> (hi,lo) bf16 split + p2
__global__ __launch_bounds__(64) void k_prep(const float* __restrict__ proto,
                                             unsigned short* __restrict__ phi,
                                             unsigned short* __restrict__ plo,
                                             float* __restrict__ p2) {
    const int p = blockIdx.x;
    const int lane = threadIdx.x;
    const float* row = proto + (size_t)p * HD;
    float acc = 0.f;
    for (int k = lane; k < HD; k += 64) {
        const float f = row[k];
        acc += f * f;
        const unsigned short h = f2bu(f);
        phi[(size_t)p * HD + k] = h;
        plo[(size_t)p * HD + k] = f2bu(f - b2f(h));
    }
#pragma unroll
    for (int m = 32; m >= 1; m >>= 1) acc += __shfl_xor(acc, m, 64);
    if (lane == 0) p2[p] = acc;
}

// ------------------------------------------------- main GEMM + epilogue
// grid 256 x block 256 (4 waves); wave handles 16 rows x all 48 protos.
// fp32 emulated via split-bf16: x.p ~= xh.ph + xh.pl + xl.ph  (3 MFMAs).
// MFMA 16x16x32 bf16: A[m=lane&15][k=quad*8+j], B[k=quad*8+j][n=lane&15],
// C/D: col=lane&15, row=quad*4+reg.
__global__ __launch_bounds__(256) void k_main(
    const float* __restrict__ x,
    const unsigned short* __restrict__ phi,
    const unsigned short* __restrict__ plo,
    const float* __restrict__ llw,       // [2,48] fp32
    const float* __restrict__ p2,
    float* __restrict__ partials,        // [gridDim][48]
    float* __restrict__ out_logits,      // [B,2]
    float* __restrict__ out_dist)        // [B,48]
{
    __shared__ float cs[NP];
    const int wave = threadIdx.x >> 6;
    const int lane = threadIdx.x & 63;
    const int quad = lane >> 4;
    const int lr   = lane & 15;
    const int rb   = (blockIdx.x * 4 + wave) * 16;

    if (threadIdx.x < NP) cs[threadIdx.x] = 0.f;
    __syncthreads();

    const float* xr = x + (size_t)(rb + lr) * HD + quad * 8;
    const unsigned short* ph0 = phi + (size_t)lr * HD + quad * 8;
    const unsigned short* ph1 = ph0 + 16 * HD;
    const unsigned short* ph2 = ph0 + 32 * HD;
    const unsigned short* pl0 = plo + (size_t)lr * HD + quad * 8;
    const unsigned short* pl1 = pl0 + 16 * HD;
    const unsigned short* pl2 = pl0 + 32 * HD;

    floatx4 acc0 = {0.f, 0.f, 0.f, 0.f};
    floatx4 acc1 = {0.f, 0.f, 0.f, 0.f};
    floatx4 acc2 = {0.f, 0.f, 0.f, 0.f};
    float x2p = 0.f;

#pragma unroll 2
    for (int kk = 0; kk < 32; ++kk) {
        const floatx4 xa = *(const floatx4*)(xr + kk * 32);
        const floatx4 xb = *(const floatx4*)(xr + kk * 32 + 4);
        short8 ah, al;
#pragma unroll
        for (int j = 0; j < 4; ++j) {
            const float f = xa[j];
            x2p += f * f;
            const unsigned short h = f2bu(f);
            ah[j] = (short)h;
            al[j] = (short)f2bu(f - b2f(h));
        }
#pragma unroll
        for (int j = 0; j < 4; ++j) {
            const float f = xb[j];
            x2p += f * f;
            const unsigned short h = f2bu(f);
            ah[4 + j] = (short)h;
            al[4 + j] = (short)f2bu(f - b2f(h));
        }
        const short8 bh0 = *(const short8*)(ph0 + kk * 32);
        const short8 bh1 = *(const short8*)(ph1 + kk * 32);
        const short8 bh2 = *(const short8*)(ph2 + kk * 32);
        const short8 bl0 = *(const short8*)(pl0 + kk * 32);
        const short8 bl1 = *(const short8*)(pl1 + kk * 32);
        const short8 bl2 = *(const short8*)(pl2 + kk * 32);
        acc0 = __builtin_amdgcn_mfma_f32_16x16x32_bf16(ah, bh0, acc0, 0, 0, 0);
        acc0 = __builtin_amdgcn_mfma_f32_16x16x32_bf16(ah, bl0, acc0, 0, 0, 0);
        acc0 = __builtin_amdgcn_mfma_f32_16x16x32_bf16(al, bh0, acc0, 0, 0, 0);
        acc1 = __builtin_amdgcn_mfma_f32_16x16x32_bf16(ah, bh1, acc1, 0, 0, 0);
        acc1 = __builtin_amdgcn_mfma_f32_16x16x32_bf16(ah, bl1, acc1, 0, 0, 0);
        acc1 = __builtin_amdgcn_mfma_f32_16x16x32_bf16(al, bh1, acc1, 0, 0, 0);
        acc2 = __builtin_amdgcn_mfma_f32_16x16x32_bf16(ah, bh2, acc2, 0, 0, 0);
        acc2 = __builtin_amdgcn_mfma_f32_16x16x32_bf16(ah, bl2, acc2, 0, 0, 0);
        acc2 = __builtin_amdgcn_mfma_f32_16x16x32_bf16(al, bh2, acc2, 0, 0, 0);
    }
    // combine quads' k-partials: full ||x_row||^2 lands on every lane of the column group
    x2p += __shfl_xor(x2p, 16, 64);
    x2p += __shfl_xor(x2p, 32, 64);

    float s0[4] = {0.f, 0.f, 0.f, 0.f};
    float s1[4] = {0.f, 0.f, 0.f, 0.f};
    floatx4 accs[3] = {acc0, acc1, acc2};

#pragma unroll
    for (int t = 0; t < 3; ++t) {
        const int p = t * 16 + lr;
        const float p2p = p2[p];
        const float w0 = llw[p];
        const float w1 = llw[NP + p];
        float cst = 0.f;
#pragma unroll
        for (int r = 0; r < 4; ++r) {
            const int row = quad * 4 + r;
            const float x2r = __shfl(x2p, row, 64);   // lane 'row' holds row rb+row
            const float d = -2.f * accs[t][r] + x2r + p2p;
            out_dist[(size_t)(rb + row) * NP + p] = d;
            const float sim = log1pf((1.f - EPSV) / (d + EPSV));
            s0[r] += sim * w0;
            s1[r] += sim * w1;
            cst += sim;
        }
        cst += __shfl_xor(cst, 16, 64);
        cst += __shfl_xor(cst, 32, 64);
        if (quad == 0) atomicAdd(&cs[p], cst);
    }

#pragma unroll
    for (int r = 0; r < 4; ++r) {
        float r0 = s0[r], r1 = s1[r];
#pragma unroll
        for (int m = 1; m <= 8; m <<= 1) {
            r0 += __shfl_xor(r0, m, 64);
            r1 += __shfl_xor(r1, m, 64);
        }
        if (lr == 0) {
            const int brow = rb + quad * 4 + r;
            out_logits[(size_t)brow * 2 + 0] = r0;
            out_logits[(size_t)brow * 2 + 1] = r1;
        }
    }

    __syncthreads();
    if (threadIdx.x < NP) partials[(size_t)blockIdx.x * NP + threadIdx.x] = cs[threadIdx.x];
}

// ------------------------------ reduce partials, argmax, v = chosen^T W2
__global__ __launch_bounds__(256) void k_matvec(
    const float* __restrict__ proto,
    const float* __restrict__ w2,        // [H,H] fp32
    const float* __restrict__ partials,  // [256][48]
    const int* __restrict__ flag,
    float* __restrict__ v)               // [H] fp32, pre-zeroed
{
    __shared__ float colsum[PPC];
    __shared__ int js;
    const int tid = threadIdx.x;
    const int idx = (flag[0] != 0) ? 1 : 0;
    if (tid < PPC) {
        float s = 0.f;
        for (int blk = 0; blk < 256; ++blk)
            s += partials[(size_t)blk * NP + idx * PPC + tid];
        colsum[tid] = s;
    }
    __syncthreads();
    if (tid == 0) {
        int bj = 0; float bv = colsum[0];
        for (int j = 1; j < PPC; ++j)
            if (colsum[j] > bv) { bv = colsum[j]; bj = j; }   // first-max, like argmax
        js = bj;
    }
    __syncthreads();

    const float* crow = proto + (size_t)(idx * PPC + js) * HD;
    const int i0 = blockIdx.x * 64;
    const int j4 = tid * 4;
    float a0 = 0.f, a1 = 0.f, a2 = 0.f, a3 = 0.f;
    for (int i = i0; i < i0 + 64; ++i) {
        const float c = crow[i];
        const floatx4 wv = *(const floatx4*)(w2 + (size_t)i * HD + j4);
        a0 += c * wv[0];
        a1 += c * wv[1];
        a2 += c * wv[2];
        a3 += c * wv[3];
    }
    atomicAdd(&v[j4 + 0], a0);
    atomicAdd(&v[j4 + 1], a1);
    atomicAdd(&v[j4 + 2], a2);
    atomicAdd(&v[j4 + 3], a3);
}

// -------------------------------------- pos[b] = v . shared[b] + bias; copy
// grid 4096 x block 256 (4 waves, one row per wave)
__global__ __launch_bounds__(256) void k_pos(
    const float* __restrict__ sh,
    const float* __restrict__ v,
    const float* __restrict__ bias,
    float* __restrict__ out_pos,
    float* __restrict__ out_copy)
{
    const int wave = threadIdx.x >> 6;
    const int lane = threadIdx.x & 63;
    const int b = blockIdx.x * 4 + wave;

    const floatx4* src = (const floatx4*)(sh + (size_t)b * HD);
    floatx4* dst = (floatx4*)(out_copy + (size_t)b * HD);
    const float* vp = v + lane * 16;
    float acc = 0.f;
#pragma unroll
    for (int c = 0; c < 4; ++c) {
        const floatx4 r = src[lane * 4 + c];
        dst[lane * 4 + c] = r;           // bit-exact pass-through
#pragma unroll
        for (int j = 0; j < 4; ++j) acc += r[j] * vp[c * 4 + j];
    }
#pragma unroll
    for (int m = 1; m <= 32; m <<= 1) acc += __shfl_xor(acc, m, 64);
    if (lane == 0) out_pos[b] = acc + bias[0];
}

extern "C" void kernel_launch(void* const* d_in, const int* in_sizes, int n_in,
                              void* d_out, int out_size, void* d_ws, size_t ws_size,
                              hipStream_t stream) {
    const float* x     = (const float*)d_in[0];  // specific_user [B,H] fp32
    const float* sh    = (const float*)d_in[1];  // shared_user   [B,H] fp32
    const float* proto = (const float*)d_in[2];  // [48,H] fp32
    const float* llw   = (const float*)d_in[3];  // [2,48] fp32
    const float* w2    = (const float*)d_in[4];  // [1,H,H] fp32
    const float* bb    = (const float*)d_in[5];  // [1] fp32
    const int*   flag  = (const int*)d_in[6];    // [1] int32

    float* out = (float*)d_out;
    // outputs concatenated flat: pos [B,1] | shared copy [B,H] | logits [B,2] | distance [B,48]
    float* out_pos    = out;
    float* out_copy   = out + BATCH;                           // 16384
    float* out_logits = out + BATCH + BATCH * HD;              // 16793600
    float* out_dist   = out + BATCH + BATCH * HD + BATCH * 2;  // 16826368

    float* ws_v    = (float*)d_ws;                 // [1024]  (zeroed: atomic target)
    float* ws_p2   = ws_v + 1024;                  // [48]
    float* ws_part = ws_v + 1088;                  // [256*48]
    unsigned short* ws_phi = (unsigned short*)(ws_v + 16384);  // [48*1024] bf16-hi
    unsigned short* ws_plo = ws_phi + NP * HD;                 // [48*1024] bf16-lo

    hipMemsetAsync(d_ws, 0, 1024 * sizeof(float), stream);
    k_prep<<<48, 64, 0, stream>>>(proto, ws_phi, ws_plo, ws_p2);
    k_main<<<256, 256, 0, stream>>>(x, ws_phi, ws_plo, llw, ws_p2, ws_part, out_logits, out_dist);
    k_matvec<<<16, 256, 0, stream>>>(proto, w2, ws_part, flag, ws_v);
    k_pos<<<4096, 256, 0, stream>>>(sh, ws_v, bb, out_pos, out_copy);
}

// Round 3
// 228.829 us; speedup vs baseline: 1.0123x; 1.0123x over previous
//
#include <hip/hip_runtime.h>
#include <hip/hip_bf16.h>

// Problem constants (from reference)
#define BATCH 16384
#define HD    1024
#define NP    48
#define PPC   24
#define EPSV  1e-4f

typedef __attribute__((ext_vector_type(8))) short  short8;
typedef __attribute__((ext_vector_type(4))) float  floatx4;

__device__ __forceinline__ float b2f(unsigned short s) {
    union { unsigned u; float f; } c; c.u = ((unsigned)s) << 16; return c.f;
}
__device__ __forceinline__ unsigned short f2bu(float f) {
    __hip_bfloat16 h = __float2bfloat16(f);  // RNE
    union { __hip_bfloat16 h; unsigned short u; } c; c.h = h; return c.u;
}

// ---------------------------------------- proto -> (hi,lo) bf16 split + p2
__global__ __launch_bounds__(64) void k_prep(const float* __restrict__ proto,
                                             unsigned short* __restrict__ phi,
                                             unsigned short* __restrict__ plo,
                                             float* __restrict__ p2) {
    const int p = blockIdx.x;
    const int lane = threadIdx.x;
    const float* row = proto + (size_t)p * HD;
    float acc = 0.f;
    for (int k = lane; k < HD; k += 64) {
        const float f = row[k];
        acc += f * f;
        const unsigned short h = f2bu(f);
        phi[(size_t)p * HD + k] = h;
        plo[(size_t)p * HD + k] = f2bu(f - b2f(h));
    }
#pragma unroll
    for (int m = 32; m >= 1; m >>= 1) acc += __shfl_xor(acc, m, 64);
    if (lane == 0) p2[p] = acc;
}

// ------------------------------------------------- main GEMM + epilogue
// grid 1024 x block 256 (4 waves). Block owns one 16-row band x all 48
// protos; each wave computes a K-quarter (256 elems), partial accumulators
// combined via LDS, wave 0 runs the epilogue. fp32 via split-bf16:
// x.p ~= xh.ph + xh.pl + xl.ph (3 MFMAs). MFMA 16x16x32 bf16 layouts:
// A[m=lane&15][k=quad*8+j], B[k=quad*8+j][n=lane&15], C/D col=lane&15,
// row=quad*4+reg.
__global__ __launch_bounds__(256, 4) void k_main(
    const float* __restrict__ x,
    const unsigned short* __restrict__ phi,
    const unsigned short* __restrict__ plo,
    const float* __restrict__ llw,       // [2,48] fp32
    const float* __restrict__ p2,
    float* __restrict__ gcol,            // [48] fp32, pre-zeroed (atomic)
    float* __restrict__ out_logits,      // [B,2]
    float* __restrict__ out_dist)        // [B,48]
{
    __shared__ float lacc[4][64][13];    // 13: pad (12-stride = 8-way conflict)
    __shared__ float lx2[4][16];
    const int wave = threadIdx.x >> 6;
    const int lane = threadIdx.x & 63;
    const int quad = lane >> 4;
    const int lr   = lane & 15;
    const int rb   = blockIdx.x * 16;
    const int ko   = wave * 256;         // this wave's K-quarter

    const float* xr = x + (size_t)(rb + lr) * HD + ko + quad * 8;
    const unsigned short* ph0 = phi + (size_t)lr * HD + ko + quad * 8;
    const unsigned short* ph1 = ph0 + 16 * HD;
    const unsigned short* ph2 = ph0 + 32 * HD;
    const unsigned short* pl0 = plo + (size_t)lr * HD + ko + quad * 8;
    const unsigned short* pl1 = pl0 + 16 * HD;
    const unsigned short* pl2 = pl0 + 32 * HD;

    floatx4 acc0 = {0.f, 0.f, 0.f, 0.f};
    floatx4 acc1 = {0.f, 0.f, 0.f, 0.f};
    floatx4 acc2 = {0.f, 0.f, 0.f, 0.f};
    float x2p = 0.f;

#pragma unroll 2
    for (int kk = 0; kk < 8; ++kk) {
        const floatx4 xa = *(const floatx4*)(xr + kk * 32);
        const floatx4 xb = *(const floatx4*)(xr + kk * 32 + 4);
        short8 ah, al;
#pragma unroll
        for (int j = 0; j < 4; ++j) {
            const float f = xa[j];
            x2p += f * f;
            const unsigned short h = f2bu(f);
            ah[j] = (short)h;
            al[j] = (short)f2bu(f - b2f(h));
        }
#pragma unroll
        for (int j = 0; j < 4; ++j) {
            const float f = xb[j];
            x2p += f * f;
            const unsigned short h = f2bu(f);
            ah[4 + j] = (short)h;
            al[4 + j] = (short)f2bu(f - b2f(h));
        }
        const short8 bh0 = *(const short8*)(ph0 + kk * 32);
        const short8 bh1 = *(const short8*)(ph1 + kk * 32);
        const short8 bh2 = *(const short8*)(ph2 + kk * 32);
        const short8 bl0 = *(const short8*)(pl0 + kk * 32);
        const short8 bl1 = *(const short8*)(pl1 + kk * 32);
        const short8 bl2 = *(const short8*)(pl2 + kk * 32);
        acc0 = __builtin_amdgcn_mfma_f32_16x16x32_bf16(ah, bh0, acc0, 0, 0, 0);
        acc0 = __builtin_amdgcn_mfma_f32_16x16x32_bf16(ah, bl0, acc0, 0, 0, 0);
        acc0 = __builtin_amdgcn_mfma_f32_16x16x32_bf16(al, bh0, acc0, 0, 0, 0);
        acc1 = __builtin_amdgcn_mfma_f32_16x16x32_bf16(ah, bh1, acc1, 0, 0, 0);
        acc1 = __builtin_amdgcn_mfma_f32_16x16x32_bf16(ah, bl1, acc1, 0, 0, 0);
        acc1 = __builtin_amdgcn_mfma_f32_16x16x32_bf16(al, bh1, acc1, 0, 0, 0);
        acc2 = __builtin_amdgcn_mfma_f32_16x16x32_bf16(ah, bh2, acc2, 0, 0, 0);
        acc2 = __builtin_amdgcn_mfma_f32_16x16x32_bf16(ah, bl2, acc2, 0, 0, 0);
        acc2 = __builtin_amdgcn_mfma_f32_16x16x32_bf16(al, bh2, acc2, 0, 0, 0);
    }
    // per-wave: x2 partial for row lr over this wave's K-quarter
    x2p += __shfl_xor(x2p, 16, 64);
    x2p += __shfl_xor(x2p, 32, 64);

    // stash partial accumulators, combine on wave 0
#pragma unroll
    for (int r = 0; r < 4; ++r) {
        lacc[wave][lane][r]     = acc0[r];
        lacc[wave][lane][4 + r] = acc1[r];
        lacc[wave][lane][8 + r] = acc2[r];
    }
    if (quad == 0) lx2[wave][lr] = x2p;
    __syncthreads();
    if (wave != 0) return;

    float facc[12];
#pragma unroll
    for (int i = 0; i < 12; ++i)
        facc[i] = lacc[0][lane][i] + lacc[1][lane][i] + lacc[2][lane][i] + lacc[3][lane][i];
    const float x2full = lx2[0][lr] + lx2[1][lr] + lx2[2][lr] + lx2[3][lr]; // row lr

    float s0[4] = {0.f, 0.f, 0.f, 0.f};
    float s1[4] = {0.f, 0.f, 0.f, 0.f};

#pragma unroll
    for (int t = 0; t < 3; ++t) {
        const int p = t * 16 + lr;
        const float p2p = p2[p];
        const float w0 = llw[p];
        const float w1 = llw[NP + p];
        float cst = 0.f;
#pragma unroll
        for (int r = 0; r < 4; ++r) {
            const int row = quad * 4 + r;
            const float x2r = __shfl(x2full, row, 64);   // lane 'row' holds row rb+row
            const float d = -2.f * facc[t * 4 + r] + x2r + p2p;
            out_dist[(size_t)(rb + row) * NP + p] = d;
            const float sim = log1pf((1.f - EPSV) / (d + EPSV));
            s0[r] += sim * w0;
            s1[r] += sim * w1;
            cst += sim;
        }
        cst += __shfl_xor(cst, 16, 64);
        cst += __shfl_xor(cst, 32, 64);
        if (quad == 0) atomicAdd(&gcol[p], cst);   // batch-wide column sum
    }

#pragma unroll
    for (int r = 0; r < 4; ++r) {
        float r0 = s0[r], r1 = s1[r];
#pragma unroll
        for (int m = 1; m <= 8; m <<= 1) {
            r0 += __shfl_xor(r0, m, 64);
            r1 += __shfl_xor(r1, m, 64);
        }
        if (lr == 0) {
            const int brow = rb + quad * 4 + r;
            out_logits[(size_t)brow * 2 + 0] = r0;
            out_logits[(size_t)brow * 2 + 1] = r1;
        }
    }
}

// ------------------------------ argmax over gcol, v = chosen^T W2
// grid 64 x block 256; every block redundantly computes jstar (48 reads),
// then handles a 16-row i-chunk of the matvec, atomicAdd into v[1024].
__global__ __launch_bounds__(256) void k_matvec(
    const float* __restrict__ proto,
    const float* __restrict__ w2,        // [H,H] fp32
    const float* __restrict__ gcol,      // [48] batch column sums
    const int* __restrict__ flag,
    float* __restrict__ v)               // [H] fp32, pre-zeroed
{
    __shared__ int js;
    const int tid = threadIdx.x;
    const int idx = (flag[0] != 0) ? 1 : 0;
    if (tid == 0) {
        const float* cs = gcol + idx * PPC;
        int bj = 0; float bv = cs[0];
        for (int j = 1; j < PPC; ++j)
            if (cs[j] > bv) { bv = cs[j]; bj = j; }   // first-max, like argmax
        js = bj;
    }
    __syncthreads();

    const float* crow = proto + (size_t)(idx * PPC + js) * HD;
    const int i0 = blockIdx.x * 16;
    const int j4 = tid * 4;
    float a0 = 0.f, a1 = 0.f, a2 = 0.f, a3 = 0.f;
#pragma unroll 4
    for (int i = i0; i < i0 + 16; ++i) {
        const float c = crow[i];
        const floatx4 wv = *(const floatx4*)(w2 + (size_t)i * HD + j4);
        a0 += c * wv[0];
        a1 += c * wv[1];
        a2 += c * wv[2];
        a3 += c * wv[3];
    }
    atomicAdd(&v[j4 + 0], a0);
    atomicAdd(&v[j4 + 1], a1);
    atomicAdd(&v[j4 + 2], a2);
    atomicAdd(&v[j4 + 3], a3);
}

// -------------------------------------- pos[b] = v . shared[b] + bias; copy
// grid 4096 x block 256 (4 waves, one row per wave). Lane-contiguous:
// chunk index c*64+lane -> each load/store instr is 64x16B contiguous (1KB).
__global__ __launch_bounds__(256) void k_pos(
    const float* __restrict__ sh,
    const float* __restrict__ v,
    const float* __restrict__ bias,
    float* __restrict__ out_pos,
    float* __restrict__ out_copy)
{
    const int wave = threadIdx.x >> 6;
    const int lane = threadIdx.x & 63;
    const int b = blockIdx.x * 4 + wave;

    const floatx4* src = (const floatx4*)(sh + (size_t)b * HD);
    floatx4* dst = (floatx4*)(out_copy + (size_t)b * HD);
    const floatx4* vv = (const floatx4*)v;
    float acc = 0.f;
#pragma unroll
    for (int c = 0; c < 4; ++c) {
        const int idx = c * 64 + lane;
        const floatx4 r = src[idx];
        __builtin_nontemporal_store(r, &dst[idx]);   // streaming copy, bit-exact
        const floatx4 vr = vv[idx];
#pragma unroll
        for (int j = 0; j < 4; ++j) acc += r[j] * vr[j];
    }
#pragma unroll
    for (int m = 1; m <= 32; m <<= 1) acc += __shfl_xor(acc, m, 64);
    if (lane == 0) out_pos[b] = acc + bias[0];
}

extern "C" void kernel_launch(void* const* d_in, const int* in_sizes, int n_in,
                              void* d_out, int out_size, void* d_ws, size_t ws_size,
                              hipStream_t stream) {
    const float* x     = (const float*)d_in[0];  // specific_user [B,H] fp32
    const float* sh    = (const float*)d_in[1];  // shared_user   [B,H] fp32
    const float* proto = (const float*)d_in[2];  // [48,H] fp32
    const float* llw   = (const float*)d_in[3];  // [2,48] fp32
    const float* w2    = (const float*)d_in[4];  // [1,H,H] fp32
    const float* bb    = (const float*)d_in[5];  // [1] fp32
    const int*   flag  = (const int*)d_in[6];    // [1] int32

    float* out = (float*)d_out;
    // outputs concatenated flat: pos [B,1] | shared copy [B,H] | logits [B,2] | distance [B,48]
    float* out_pos    = out;
    float* out_copy   = out + BATCH;                           // 16384
    float* out_logits = out + BATCH + BATCH * HD;              // 16793600
    float* out_dist   = out + BATCH + BATCH * HD + BATCH * 2;  // 16826368

    float* ws_v    = (float*)d_ws;                 // [1024]  (zeroed: atomic target)
    float* ws_col  = ws_v + 1024;                  // [48]    (zeroed: atomic target)
    float* ws_p2   = ws_v + 1088;                  // [48]
    unsigned short* ws_phi = (unsigned short*)(ws_v + 16384);  // [48*1024] bf16-hi
    unsigned short* ws_plo = ws_phi + NP * HD;                 // [48*1024] bf16-lo

    hipMemsetAsync(d_ws, 0, 8192, stream);         // v + gcol
    k_prep<<<48, 64, 0, stream>>>(proto, ws_phi, ws_plo, ws_p2);
    k_main<<<1024, 256, 0, stream>>>(x, ws_phi, ws_plo, llw, ws_p2, ws_col, out_logits, out_dist);
    k_matvec<<<64, 256, 0, stream>>>(proto, w2, ws_col, flag, ws_v);
    k_pos<<<4096, 256, 0, stream>>>(sh, ws_v, bb, out_pos, out_copy);
}